// Round 7
// baseline (24.294 us; speedup 1.0000x reference)
//
#include <hip/hip_runtime.h>

#define NN 256
#define NITER 20
static constexpr float KK   = 14.426950408889634f; // (1/tau)*log2(e), tau=0.1
static constexpr float DREF = 2.0f / 255.0f;       // linspace spacing

template<int CTRL, int RM>
__device__ __forceinline__ float dppadd(float x) {
  int v = __builtin_amdgcn_update_dpp(0, __float_as_int(x), CTRL, RM, 0xF, true);
  return x + __int_as_float(v);
}
template<int CTRL, int RM>
__device__ __forceinline__ int dppaddi(int x) {
  int v = __builtin_amdgcn_update_dpp(0, x, CTRL, RM, 0xF, true);
  return x + v;
}
__device__ __forceinline__ float rlane(float v, int l) {
  return __int_as_float(__builtin_amdgcn_readlane(__float_as_int(v), l));
}
__device__ __forceinline__ float rcpf(float x) {
  float r; asm("v_rcp_f32 %0, %1" : "=v"(r) : "v"(x)); return r;
}
// inclusive wave prefix scan over 64 lane-totals (proven rounds 2-5)
__device__ __forceinline__ float wavescan(float t) {
  float s = t;
  s = dppadd<0x111,0xF>(s); s = dppadd<0x112,0xF>(s);
  s = dppadd<0x114,0xF>(s); s = dppadd<0x118,0xF>(s);
  s = dppadd<0x142,0xA>(s); s = dppadd<0x143,0xC>(s);
  return s;
}

__global__ __launch_bounds__(64)
void sinkhorn_merged(const float* __restrict__ x,
                     const float* __restrict__ xn,
                     const float* __restrict__ refv,
                     float* __restrict__ out)
{
  // Single-wave workgroup: no barriers; per-wave in-order DS ordering.
  // LDS is SETUP-ONLY (+ final output staging). Main loop: zero LDS ops.
  __shared__ __align__(16) unsigned hist2[512];  // sub-bucket counts
  __shared__ __align__(16) int      excl2[512];  // exclusive sub-bucket prefix
  __shared__ __align__(16) float2   AR[512];     // (EpR,EmR): masked ref-event coeffs
  __shared__ __align__(16) float2   AX[512];     // (EpX,EmX): masked xs-event coeffs
  __shared__ __align__(16) float2   WO[512];     // (x weight, orig idx bitcast)
  __shared__ __align__(16) float    outA[NN];    // output staging

  const int lane = threadIdx.x;     // 0..63
  const int j4 = lane * 4, j8 = lane * 8;
  const size_t base = (size_t)blockIdx.x * NN;

  float xnv[4], xv[4], rv[4];
  { float4 t = *(const float4*)(xn + base + j4); xnv[0]=t.x; xnv[1]=t.y; xnv[2]=t.z; xnv[3]=t.w; }
  { float4 t = *(const float4*)(x  + base + j4); xv[0]=t.x;  xv[1]=t.y;  xv[2]=t.z;  xv[3]=t.w; }
  { float4 t = *(const float4*)(refv + j4);      rv[0]=t.x;  rv[1]=t.y;  rv[2]=t.z;  rv[3]=t.w; }

  // ---- build merged order: 512 sub-buckets (2*cell + geBit), exact compares ----
  *(uint4*)&hist2[j8]     = make_uint4(0u,0u,0u,0u);
  *(uint4*)&hist2[j8 + 4] = make_uint4(0u,0u,0u,0u);
  int key[4]; unsigned rtn[4]; float vc[4];
  #pragma unroll
  for (int t = 0; t < 4; ++t) {
    vc[t] = fminf(fmaxf(xnv[t], -1.0f), 1.0f);   // clamp = exact row-shift invariance
    int cb = (int)fmaf(vc[t], 127.5f, 127.5f);   // floor cell
    int ge = (vc[t] >= fmaf((float)cb, DREF, -1.0f)) ? 1 : 0;
    key[t] = 2 * cb + ge;                        // [0,512)
    rtn[t] = atomicAdd(&hist2[key[t]], 1u);      // intra-sub-bucket rank
  }
  uint4 h0 = *(uint4*)&hist2[j8];                 // in-order DS: after all atomics
  uint4 h1 = *(uint4*)&hist2[j8 + 4];
  int ie1 = (int)h0.x, ie2 = ie1 + (int)h0.y, ie3 = ie2 + (int)h0.z, ie4 = ie3 + (int)h0.w;
  int ie5 = ie4 + (int)h1.x, ie6 = ie5 + (int)h1.y, ie7 = ie6 + (int)h1.z, th = ie7 + (int)h1.w;
  int sH = th;
  sH = dppaddi<0x111,0xF>(sH); sH = dppaddi<0x112,0xF>(sH);
  sH = dppaddi<0x114,0xF>(sH); sH = dppaddi<0x118,0xF>(sH);
  sH = dppaddi<0x142,0xA>(sH); sH = dppaddi<0x143,0xC>(sH);
  const int offH = sH - th;
  *(int4*)&excl2[j8]     = make_int4(offH, offH+ie1, offH+ie2, offH+ie3);
  *(int4*)&excl2[j8 + 4] = make_int4(offH+ie4, offH+ie5, offH+ie6, offH+ie7);
  // merged position of ref_j (j=j4+t): lane-local (#xs before = incl. prefix thru sub-bucket 2t)
  const int ieOdd[4] = { ie1, ie3, ie5, ie7 };
  int posR[4], posX[4];
  #pragma unroll
  for (int t = 0; t < 4; ++t) posR[t] = offH + ieOdd[t] + j4 + t;
  // merged position of xs: #xs-before (gather) + intra rank + #refs-before = (key+1)>>1
  #pragma unroll
  for (int t = 0; t < 4; ++t) posX[t] = excl2[key[t]] + (int)rtn[t] + ((key[t] + 1) >> 1);

  // ---- scatter per-position constants (pre-masked coefficient pairs) ----
  #pragma unroll
  for (int t = 0; t < 4; ++t) {
    float rp = exp2f( KK * rv[t]), rm = exp2f(-KK * rv[t]);
    float qp = exp2f( KK * vc[t]), qm = exp2f(-KK * vc[t]);
    AR[posR[t]] = make_float2(rp, rm);
    AX[posR[t]] = make_float2(0.f, 0.f);
    WO[posR[t]] = make_float2(xv[t], 0.f);
    AR[posX[t]] = make_float2(0.f, 0.f);
    AX[posX[t]] = make_float2(qp, qm);
    WO[posX[t]] = make_float2(0.f, __int_as_float(j4 + t));
  }
  // ---- readback own 8 merged slots into registers ----
  float EpR[8], EmR[8], EpX[8], EmX[8], Epq[8], Emq[8], mX[8], mR[8], pot[8];
  #pragma unroll
  for (int i = 0; i < 8; i += 2) {
    float4 r = *(float4*)&AR[j8 + i];
    EpR[i] = r.x; EmR[i] = r.y; EpR[i+1] = r.z; EmR[i+1] = r.w;
    float4 q = *(float4*)&AX[j8 + i];
    EpX[i] = q.x; EmX[i] = q.y; EpX[i+1] = q.z; EmX[i+1] = q.w;
  }
  #pragma unroll
  for (int i = 0; i < 8; ++i) {
    Epq[i] = EpR[i] + EpX[i];  Emq[i] = EmR[i] + EmX[i];   // unmasked query factors
    mX[i] = (EpX[i] > 0.f) ? 1.f : 0.f;  mR[i] = 1.f - mX[i];
    pot[i] = 1.f;
  }
  const int row = lane >> 4;

  // one half-pass fully in registers. Prefix A: front-accumulated tree.
  // Suffix D: TRUE suffix scan (tail-accumulated; positives only — no
  // cancellation; this was round 6's fatal bug via CT - prefix).
  auto pass = [&](const float (&cp)[8], const float (&cm)[8], const float (&sel)[8]) {
    float a[8], c[8], ea[8], sc[8], ta;
    #pragma unroll
    for (int i = 0; i < 8; ++i) { a[i] = cp[i] * pot[i]; c[i] = cm[i] * pot[i]; }
    { float u01=a[0]+a[1], u23=a[2]+a[3], u03=u01+u23, u45=a[4]+a[5];
      ea[0]=0.f; ea[1]=a[0]; ea[2]=u01; ea[3]=u01+a[2]; ea[4]=u03;
      ea[5]=u03+a[4]; ea[6]=u03+u45; ea[7]=ea[6]+a[6]; ta=ea[7]+a[7]; }
    sc[7]=c[7]; sc[6]=c[6]+sc[7]; sc[5]=c[5]+sc[6]; sc[4]=c[4]+sc[5];
    sc[3]=c[3]+sc[4]; sc[2]=c[2]+sc[3]; sc[1]=c[1]+sc[2]; sc[0]=c[0]+sc[1];
    const float tc = sc[0];
    float sA = wavescan(ta);
    float offA = sA - ta;
    float sQ = tc;                       // within-row inclusive suffix of lane totals
    sQ = dppadd<0x101,0xF>(sQ);
    sQ = dppadd<0x102,0xF>(sQ);
    sQ = dppadd<0x104,0xF>(sQ);
    sQ = dppadd<0x108,0xF>(sQ);
    float q1 = rlane(sQ, 16), q2 = rlane(sQ, 32), q3 = rlane(sQ, 48);
    float offQ = sQ - tc;
    offQ += (row < 1) ? q1 : 0.f;
    offQ += (row < 2) ? q2 : 0.f;
    offQ += (row < 3) ? q3 : 0.f;
    #pragma unroll
    for (int i = 0; i < 8; ++i) {
      float A = offA + ea[i];
      float D = offQ + sc[i];            // c[i]==0 at query slots -> exclusive
      float S = fmaf(Emq[i], A, Epq[i] * D);
      float r = rcpf(S);
      pot[i] = fmaf(sel[i], r - pot[i], pot[i]); // update only selected type
    }
  };

  #pragma unroll 1
  for (int it = 0; it < NITER; ++it) {
    pass(EpR, EmR, mX);   // row pass: updates vR at xs positions
    pass(EpX, EmX, mR);   // col pass: updates vC at ref positions
  }

  // ---- final weighted row pass: out[orig_m] = vR_m * sum_j 2^{-k|xs-ref|} vC_j x_j ----
  {
    float xw[8]; int og[8];
    #pragma unroll
    for (int i = 0; i < 8; i += 2) {
      float4 w = *(float4*)&WO[j8 + i];
      xw[i] = w.x; og[i] = __float_as_int(w.y);
      xw[i+1] = w.z; og[i+1] = __float_as_int(w.w);
    }
    float a[8], c[8], ea[8], sc[8], ta;
    #pragma unroll
    for (int i = 0; i < 8; ++i) { float g = xw[i] * pot[i]; a[i] = EpR[i] * g; c[i] = EmR[i] * g; }
    { float u01=a[0]+a[1], u23=a[2]+a[3], u03=u01+u23, u45=a[4]+a[5];
      ea[0]=0.f; ea[1]=a[0]; ea[2]=u01; ea[3]=u01+a[2]; ea[4]=u03;
      ea[5]=u03+a[4]; ea[6]=u03+u45; ea[7]=ea[6]+a[6]; ta=ea[7]+a[7]; }
    sc[7]=c[7]; sc[6]=c[6]+sc[7]; sc[5]=c[5]+sc[6]; sc[4]=c[4]+sc[5];
    sc[3]=c[3]+sc[4]; sc[2]=c[2]+sc[3]; sc[1]=c[1]+sc[2]; sc[0]=c[0]+sc[1];
    const float tc = sc[0];
    float sA = wavescan(ta);
    float offA = sA - ta;
    float sQ = tc;
    sQ = dppadd<0x101,0xF>(sQ);
    sQ = dppadd<0x102,0xF>(sQ);
    sQ = dppadd<0x104,0xF>(sQ);
    sQ = dppadd<0x108,0xF>(sQ);
    float q1 = rlane(sQ, 16), q2 = rlane(sQ, 32), q3 = rlane(sQ, 48);
    float offQ = sQ - tc;
    offQ += (row < 1) ? q1 : 0.f;
    offQ += (row < 2) ? q2 : 0.f;
    offQ += (row < 3) ? q3 : 0.f;
    #pragma unroll
    for (int i = 0; i < 8; ++i) {
      float A = offA + ea[i];
      float D = offQ + sc[i];
      float S = fmaf(Emq[i], A, Epq[i] * D);
      float val = pot[i] * S;
      if (mX[i] != 0.f) outA[og[i]] = val;     // stage per-row output
    }
    float4 o = *(float4*)&outA[j4];             // in-order DS: after all writes
    *(float4*)(out + base + j4) = o;            // coalesced store
  }
}

extern "C" void kernel_launch(void* const* d_in, const int* in_sizes, int n_in,
                              void* d_out, int out_size, void* d_ws, size_t ws_size,
                              hipStream_t stream) {
  const float* x    = (const float*)d_in[0];
  const float* xnrm = (const float*)d_in[1];
  const float* refv = (const float*)d_in[2];
  float* out = (float*)d_out;
  const int B = in_sizes[0] / NN;  // 2048
  sinkhorn_merged<<<dim3(B), dim3(64), 0, stream>>>(x, xnrm, refv, out);
}